// Round 7
// baseline (253.614 us; speedup 1.0000x reference)
//
#include <hip/hip_runtime.h>
#include <stdint.h>
#include <stddef.h>

// Problem constants (B=2,S=2048,D=1024,H=16,HD=64)
#define SCALE_LOG2E 11.541560327111707f   // 8 * log2(e): folded into Q projection
#define E8 4194304                        // 4096*1024 plane (elements)
#define M1 1048576                        // 1024*1024 plane
#define NROW 65536                        // B*H*S rows

typedef __attribute__((ext_vector_type(8))) _Float16 f16x8;
typedef __attribute__((ext_vector_type(4))) _Float16 f16x4;
typedef __attribute__((ext_vector_type(4))) float f32x4;

#if __has_builtin(__builtin_amdgcn_exp2f)
#define EXP2F(x) __builtin_amdgcn_exp2f(x)
#else
#define EXP2F(x) exp2f(x)
#endif

__device__ __forceinline__ f32x4 mfma_f16(f16x8 a, f16x8 b, f32x4 c) {
  return __builtin_amdgcn_mfma_f32_16x16x32_f16(a, b, c, 0, 0, 0);
}

// async global->LDS, 16B per lane. LDS dest is wave-uniform base + lane*16.
__device__ __forceinline__ void async16(const void* g, void* lds) {
  __builtin_amdgcn_global_load_lds(
      (const __attribute__((address_space(1))) unsigned int*)g,
      (__attribute__((address_space(3))) unsigned int*)lds, 16, 0, 0);
}

__device__ __forceinline__ unsigned int hbits(_Float16 h) {
  return (unsigned int)__builtin_bit_cast(unsigned short, h);
}

typedef union { unsigned int u[4]; f16x8 h; } PU;

// ---------------- merged fp32 -> fp16 conversion (all 7 tensors) ----------------
__global__ void prep_all(const float* __restrict__ q, const float* __restrict__ k,
                         const float* __restrict__ v,
                         const float* __restrict__ wq, const float* __restrict__ wk,
                         const float* __restrict__ wv, const float* __restrict__ wo,
                         _Float16* __restrict__ Xf, _Float16* __restrict__ Wf) {
  const int gid = blockIdx.x;
  const float* src;
  _Float16* dst;
  int i;
  if (gid < 12288) {
    const int z = gid >> 12;
    src = (z == 0) ? q : (z == 1) ? k : v;
    dst = Xf + (size_t)z * E8;
    i = (gid & 4095) * 256 + threadIdx.x;
  } else {
    const int g2 = gid - 12288;
    const int z = g2 >> 10;
    src = (z == 0) ? wq : (z == 1) ? wk : (z == 2) ? wv : wo;
    dst = Wf + (size_t)z * M1;
    i = (g2 & 1023) * 256 + threadIdx.x;
  }
  float4 x = ((const float4*)src)[i];
  f16x4 h = {(_Float16)x.x, (_Float16)x.y, (_Float16)x.z, (_Float16)x.w};
  ((f16x4*)dst)[i] = h;
}

// ---------------- merged Q/K/V projection: fp16 GEMM, LDS double-buffered ----------------
__global__ __launch_bounds__(256, 3) void gemm_qkv(
    const _Float16* __restrict__ Xf,    // 3 planes stride E8
    const _Float16* __restrict__ Wf,    // 4 planes stride M1
    const float* __restrict__ bq, const float* __restrict__ bk,
    const float* __restrict__ bv,
    _Float16* __restrict__ Of)
{
  __shared__ _Float16 SMEM[16384];      // staging dbuf (2x4096 A + 2x4096 B) / epilogue Ct
  _Float16* LA = SMEM;                  // [2][4096]
  _Float16* LB = SMEM + 8192;           // [2][4096]
  const int z = blockIdx.z;
  const int tid = threadIdx.x;
  const int lane = tid & 63;
  const int wv = tid >> 6;
  const int wm = wv >> 1, wn = wv & 1;
  const int rl = lane & 15, qd = lane >> 4;
  const int m0 = blockIdx.y * 128, n0 = blockIdx.x * 128;

  const _Float16* A0 = Xf + (size_t)z * E8;
  const _Float16* W0 = Wf + (size_t)z * M1;
  const float* bias = (z == 0) ? bq : (z == 1) ? bk : bv;

  f32x4 acc[4][4];
#pragma unroll
  for (int i = 0; i < 4; i++)
#pragma unroll
    for (int j = 0; j < 4; j++) acc[i][j] = f32x4{0.f, 0.f, 0.f, 0.f};

  const int srow = wv * 32 + (lane >> 2);
  const int scol = (lane & 3) * 8;

  auto stage = [&](int k0, int buf) {
    const _Float16* ga = A0 + (size_t)(m0 + srow) * 1024 + k0 + scol;
    async16(ga, &LA[buf * 4096 + wv * 1024]);
    async16(ga + 16 * 1024, &LA[buf * 4096 + wv * 1024 + 512]);
    const _Float16* gb = W0 + (size_t)(n0 + srow) * 1024 + k0 + scol;
    async16(gb, &LB[buf * 4096 + wv * 1024]);
    async16(gb + 16 * 1024, &LB[buf * 4096 + wv * 1024 + 512]);
  };

  stage(0, 0);
  for (int t = 0; t < 32; t++) {
    const int buf = t & 1;
    __syncthreads();                          // DMA(t) drained; all done with buf^1
    if (t + 1 < 32) stage((t + 1) * 32, buf ^ 1);
    f16x8 af[4], bfr[4];
#pragma unroll
    for (int i = 0; i < 4; i++) af[i] = *(const f16x8*)&LA[buf * 4096 + (wm * 64 + i * 16 + rl) * 32 + qd * 8];
#pragma unroll
    for (int j = 0; j < 4; j++) bfr[j] = *(const f16x8*)&LB[buf * 4096 + (wn * 64 + j * 16 + rl) * 32 + qd * 8];
#pragma unroll
    for (int i = 0; i < 4; i++)
#pragma unroll
      for (int j = 0; j < 4; j++) acc[i][j] = mfma_f16(af[i], bfr[j], acc[i][j]);
  }

  if (z == 2) {
    // V^T epilogue: Vt[b,h,e,s], 4 contiguous s per store
#pragma unroll
    for (int j = 0; j < 4; j++) {
      const int nn = n0 + wn * 64 + j * 16 + rl;
      const float bj = bias[nn];
      const int hh = nn >> 6, e = nn & 63;
#pragma unroll
      for (int i = 0; i < 4; i++) {
        const int mm = m0 + wm * 64 + i * 16 + qd * 4;
        const int b = mm >> 11, s = mm & 2047;
        f16x4 pk = {(_Float16)(acc[i][j][0] + bj), (_Float16)(acc[i][j][1] + bj),
                    (_Float16)(acc[i][j][2] + bj), (_Float16)(acc[i][j][3] + bj)};
        *(f16x4*)(Of + 2 * (size_t)E8 + (((size_t)((b * 16 + hh) * 64 + e)) << 11) + s) = pk;
      }
    }
  } else {
    // LDS-transposed coalesced epilogue: Ct[128][128] with qd-xor column swizzle
    const float scl = (z == 0) ? SCALE_LOG2E : 1.0f;
    _Float16* base = Of + (size_t)z * E8;
    __syncthreads();                          // staging LDS now free
#pragma unroll
    for (int j = 0; j < 4; j++) {
      const int nl = wn * 64 + j * 16 + rl;
      const float bj = bias[n0 + nl];
#pragma unroll
      for (int i = 0; i < 4; i++) {
        const int ml = wm * 64 + i * 16 + qd * 4;
        const int np = nl ^ (qd << 4);        // (m>>2)&3 == qd here
#pragma unroll
        for (int r = 0; r < 4; r++)
          SMEM[(ml + r) * 128 + np] = (_Float16)((acc[i][j][r] + bj) * scl);
      }
    }
    __syncthreads();
#pragma unroll
    for (int it2 = 0; it2 < 8; it2++) {
      const int m = (it2 * 256 + tid) >> 4;   // 0..127
      const int col8 = (tid & 15) * 8;
      const int np = col8 ^ (((m >> 2) & 3) << 4);
      f16x8 vrow = *(const f16x8*)&SMEM[m * 128 + np];
      const int sg = m0 + m;
      const int b = sg >> 11, s = sg & 2047;
      const int nn = n0 + col8;
      const int hh = nn >> 6, e = nn & 63;
      *(f16x8*)(base + (((size_t)((b * 16 + hh) * 2048 + s)) << 6) + e) = vrow;
    }
  }
}

// ---------------- flash attention v7: split-KV-2, bpermute P-transform ----------------
// grid (16, 2, 32): x = q-block (128 rows), y = kv half, z = bh. Block 256
// (4 waves x 32 q, mt=2). LDS = K/V dbuf only (32 KB) -> 4 blocks/CU, no tail.
// P C->B-operand via ds_bpermute (no LDS round trip, no barrier).
__global__ __launch_bounds__(256, 4) void attn_kernel(
    const _Float16* __restrict__ Qb,   // [B,H,S,HD], pre-scaled by 8*log2e
    const _Float16* __restrict__ Kb,   // [B,H,S,HD]
    const _Float16* __restrict__ Vt,   // [B,H,HD,S]
    _Float16* __restrict__ Op,         // [2][NROW][64] f16 partial O^T (unnormalized)
    float2* __restrict__ ML)           // [2][NROW] (m, l)
{
  __shared__ _Float16 Ks[2][4096];     // dbuf [64 keys][64 d], xor-swizzled 16B chunks
  __shared__ _Float16 Vs[2][4096];     // dbuf [64 d][64 keys], same swizzle
  const int tid = threadIdx.x;
  const int lane = tid & 63;
  const int wv = tid >> 6;
  const int rl = lane & 15, qd = lane >> 4;
  const int bh = blockIdx.z;
  const int half = blockIdx.y;
  const int kvb = half * 1024;
  const int q0 = blockIdx.x * 128 + wv * 32;

  // bpermute source-lane byte addresses for the P C->B transform
  const int alo = ((((qd & 1) << 5) + rl) << 2);  // keys j0..3 source lane
  const int ahi = alo + 64;                       // keys j4..7 source lane (+16 lanes)
  const bool selA = (qd < 2);                     // nt = kk2*2 (A) vs kk2*2+1 (B)

  // Q as B-operand fragments [mt][kk]
  f16x8 qf[2][2];
#pragma unroll
  for (int mt = 0; mt < 2; mt++)
#pragma unroll
    for (int kk = 0; kk < 2; kk++)
      qf[mt][kk] = *(const f16x8*)(Qb + ((size_t)bh * 2048 + q0 + mt * 16 + rl) * 64 +
                                   kk * 32 + qd * 8);

  float m_[2] = {-1e30f, -1e30f}, l_[2] = {0.f, 0.f};  // l_ per-lane partial
  f32x4 o[2][4];
#pragma unroll
  for (int mt = 0; mt < 2; mt++)
#pragma unroll
    for (int jt = 0; jt < 4; jt++) o[mt][jt] = f32x4{0.f, 0.f, 0.f, 0.f};

  auto stage = [&](int kv, int buf) {
#pragma unroll
    for (int it = 0; it < 2; it++) {
      const int cI = it * 256 + tid;           // chunk index 0..511
      const int row = cI >> 3;
      const int c = (cI & 7) ^ (row & 7);
      const int dst = (it * 256 + wv * 64) * 8;
      async16(Kb + ((size_t)bh * 2048 + kv + row) * 64 + c * 8, &Ks[buf][dst]);
      async16(Vt + ((size_t)bh * 64 + row) * 2048 + kv + c * 8, &Vs[buf][dst]);
    }
  };

  stage(kvb, 0);

  for (int t = 0; t < 16; t++) {
    const int buf = t & 1;
    __syncthreads();                           // DMA(t) drained; all done reading buf^1
    if (t + 1 < 16) stage(kvb + (t + 1) * 64, buf ^ 1);

    // ---- QK^T (S^T): sc[mt][nt]; key = nt*16 + qd*4 + r, q = q0 + mt*16 + rl ----
    f32x4 sc[2][4];
#pragma unroll
    for (int mt = 0; mt < 2; mt++)
#pragma unroll
      for (int nt = 0; nt < 4; nt++) sc[mt][nt] = f32x4{0.f, 0.f, 0.f, 0.f};
#pragma unroll
    for (int nt = 0; nt < 4; nt++) {
      const int ro = (nt * 16 + rl) * 64;
#pragma unroll
      for (int kk = 0; kk < 2; kk++) {
        const int cc = (((kk * 4 + qd) ^ (rl & 7)) << 3);
        f16x8 kh = *(const f16x8*)&Ks[buf][ro + cc];
#pragma unroll
        for (int mt = 0; mt < 2; mt++)
          sc[mt][nt] = mfma_f16(kh, qf[mt][kk], sc[mt][nt]);
      }
    }

    // ---- online softmax (exp2 domain): tree reductions, per-lane l partial ----
    unsigned int pw[2][4][2];                  // packed P^T f16 pairs [mt][nt][word]
#pragma unroll
    for (int mt = 0; mt < 2; mt++) {
      float tm[4];
#pragma unroll
      for (int nt = 0; nt < 4; nt++)
        tm[nt] = fmaxf(fmaxf(sc[mt][nt][0], sc[mt][nt][1]),
                       fmaxf(sc[mt][nt][2], sc[mt][nt][3]));
      float mloc = fmaxf(fmaxf(tm[0], tm[1]), fmaxf(tm[2], tm[3]));
      float mx = fmaxf(mloc, __shfl_xor(mloc, 16));
      mx = fmaxf(mx, __shfl_xor(mx, 32));
      float ts[4];
#pragma unroll
      for (int nt = 0; nt < 4; nt++) {
        float p0 = EXP2F(sc[mt][nt][0] - mloc);
        float p1 = EXP2F(sc[mt][nt][1] - mloc);
        float p2 = EXP2F(sc[mt][nt][2] - mloc);
        float p3 = EXP2F(sc[mt][nt][3] - mloc);
        sc[mt][nt][0] = p0; sc[mt][nt][1] = p1;
        sc[mt][nt][2] = p2; sc[mt][nt][3] = p3;
        ts[nt] = (p0 + p1) + (p2 + p3);
      }
      const float sm = (ts[0] + ts[1]) + (ts[2] + ts[3]);
      const float mold = m_[mt];
      const float mnew = fmaxf(mold, mx);
      m_[mt] = mnew;
      const float cf = EXP2F(mloc - mnew);     // per-lane correction
      if (__any(mnew > mold)) {
        const float al = EXP2F(mold - mnew);   // row-wide (1.0 where unchanged)
        l_[mt] = l_[mt] * al + sm * cf;
#pragma unroll
        for (int jt = 0; jt < 4; jt++)
#pragma unroll
          for (int r = 0; r < 4; r++) o[mt][jt][r] *= al;
      } else {
        l_[mt] += sm * cf;
      }
      // pack cf-corrected P^T to f16 pairs (keys +0,+1 | +2,+3 per nt)
#pragma unroll
      for (int nt = 0; nt < 4; nt++) {
        _Float16 h0 = (_Float16)(sc[mt][nt][0] * cf);
        _Float16 h1 = (_Float16)(sc[mt][nt][1] * cf);
        _Float16 h2 = (_Float16)(sc[mt][nt][2] * cf);
        _Float16 h3 = (_Float16)(sc[mt][nt][3] * cf);
        pw[mt][nt][0] = hbits(h0) | (hbits(h1) << 16);
        pw[mt][nt][1] = hbits(h2) | (hbits(h3) << 16);
      }
    }

    // ---- PV: O^T += V^T · P^T; P B-fragments via ds_bpermute ----
#pragma unroll
    for (int kk2 = 0; kk2 < 2; kk2++) {
      f16x8 pf[2];
#pragma unroll
      for (int mt = 0; mt < 2; mt++) {
        const int na = kk2 * 2, nb = na + 1;
        PU pu;
        {
          unsigned int a = __builtin_amdgcn_ds_bpermute(alo, (int)pw[mt][na][0]);
          unsigned int b = __builtin_amdgcn_ds_bpermute(alo, (int)pw[mt][nb][0]);
          pu.u[0] = selA ? a : b;
        }
        {
          unsigned int a = __builtin_amdgcn_ds_bpermute(alo, (int)pw[mt][na][1]);
          unsigned int b = __builtin_amdgcn_ds_bpermute(alo, (int)pw[mt][nb][1]);
          pu.u[1] = selA ? a : b;
        }
        {
          unsigned int a = __builtin_amdgcn_ds_bpermute(ahi, (int)pw[mt][na][0]);
          unsigned int b = __builtin_amdgcn_ds_bpermute(ahi, (int)pw[mt][nb][0]);
          pu.u[2] = selA ? a : b;
        }
        {
          unsigned int a = __builtin_amdgcn_ds_bpermute(ahi, (int)pw[mt][na][1]);
          unsigned int b = __builtin_amdgcn_ds_bpermute(ahi, (int)pw[mt][nb][1]);
          pu.u[3] = selA ? a : b;
        }
        pf[mt] = pu.h;
      }
#pragma unroll
      for (int jt = 0; jt < 4; jt++) {
        const int cc = (((kk2 * 4 + qd) ^ (rl & 7)) << 3);
        f16x8 vv = *(const f16x8*)&Vs[buf][(jt * 16 + rl) * 64 + cc];
#pragma unroll
        for (int mt = 0; mt < 2; mt++)
          o[mt][jt] = mfma_f16(vv, pf[mt], o[mt][jt]);
      }
    }
  }

  // epilogue: reduce l over qd-lanes, write f16 partials (unnormalized)
#pragma unroll
  for (int mt = 0; mt < 2; mt++) {
    float lt = l_[mt] + __shfl_xor(l_[mt], 16);
    lt += __shfl_xor(lt, 32);
    const size_t row = (size_t)bh * 2048 + q0 + mt * 16 + rl;
    _Float16* op = Op + ((size_t)half * NROW + row) * 64;
#pragma unroll
    for (int jt = 0; jt < 4; jt++) {
      f16x4 pk = {(_Float16)o[mt][jt][0], (_Float16)o[mt][jt][1],
                  (_Float16)o[mt][jt][2], (_Float16)o[mt][jt][3]};
      *(f16x4*)(op + jt * 16 + qd * 4) = pk;
    }
    if (qd == 0) ML[(size_t)half * NROW + row] = make_float2(m_[mt], lt);
  }
}

// ---------------- merge the two KV halves ----------------
__global__ void merge_kernel(const _Float16* __restrict__ Op,
                             const float2* __restrict__ ML,
                             _Float16* __restrict__ Xo) {
  const int t = threadIdx.x;
  const int row = blockIdx.x * 16 + (t >> 4);
  const int d0 = (t & 15) * 4;
  const float2 ml1 = ML[row];
  const float2 ml2 = ML[NROW + row];
  const float m = fmaxf(ml1.x, ml2.x);
  const float w1 = EXP2F(ml1.x - m), w2 = EXP2F(ml2.x - m);
  const float inv = 1.0f / (ml1.y * w1 + ml2.y * w2);
  f16x4 o1 = *(const f16x4*)(Op + (size_t)row * 64 + d0);
  f16x4 o2 = *(const f16x4*)(Op + (size_t)NROW * 64 + (size_t)row * 64 + d0);
  const int bh = row >> 11, q = row & 2047;
  const int b = bh >> 4, hh = bh & 15;
  f16x4 pk = {(_Float16)(((float)o1[0] * w1 + (float)o2[0] * w2) * inv),
              (_Float16)(((float)o1[1] * w1 + (float)o2[1] * w2) * inv),
              (_Float16)(((float)o1[2] * w1 + (float)o2[2] * w2) * inv),
              (_Float16)(((float)o1[3] * w1 + (float)o2[3] * w2) * inv)};
  *(f16x4*)(Xo + ((size_t)(b * 2048 + q)) * 1024 + hh * 64 + d0) = pk;
}

// ---------------- output projection: 64x128 tile, dbuf, fp32 out ----------------
__global__ __launch_bounds__(256, 2) void gemm_out(
    const _Float16* __restrict__ A0,
    const _Float16* __restrict__ W0,
    const float* __restrict__ bias,
    float* __restrict__ out)
{
  __shared__ _Float16 LA[2][2048];   // 64 x 32
  __shared__ _Float16 LB[2][4096];   // 128 x 32
  const int tid = threadIdx.x;
  const int lane = tid & 63;
  const int wv = tid >> 6;
  const int wm = wv >> 1, wn = wv & 1;
  const int rl = lane & 15, qd = lane >> 4;
  const int m0 = blockIdx.y * 64, n0 = blockIdx.x * 128;

  f32x4 acc[2][4];
#pragma unroll
  for (int i = 0; i < 2; i++)
#pragma unroll
    for (int j = 0; j < 4; j++) acc[i][j] = f32x4{0.f, 0.f, 0.f, 0.f};

  auto stage = [&](int k0, int buf) {
    {  // A: 256 chunks, 1 per thread
      const int row = tid >> 2, c = tid & 3;
      async16(A0 + (size_t)(m0 + row) * 1024 + k0 + c * 8, &LA[buf][wv * 512]);
    }
#pragma unroll
    for (int it = 0; it < 2; it++) {  // B: 512 chunks, 2 per thread
      const int cI = it * 256 + tid;
      const int row = cI >> 2, c = cI & 3;
      async16(W0 + (size_t)(n0 + row) * 1024 + k0 + c * 8,
              &LB[buf][it * 2048 + wv * 512]);
    }
  };

  stage(0, 0);
  for (int t = 0; t < 32; t++) {
    const int buf = t & 1;
    __syncthreads();
    if (t + 1 < 32) stage((t + 1) * 32, buf ^ 1);
    f16x8 af[2], bfr[4];
#pragma unroll
    for (int i = 0; i < 2; i++) af[i] = *(const f16x8*)&LA[buf][(wm * 32 + i * 16 + rl) * 32 + qd * 8];
#pragma unroll
    for (int j = 0; j < 4; j++) bfr[j] = *(const f16x8*)&LB[buf][(wn * 64 + j * 16 + rl) * 32 + qd * 8];
#pragma unroll
    for (int i = 0; i < 2; i++)
#pragma unroll
      for (int j = 0; j < 4; j++) acc[i][j] = mfma_f16(af[i], bfr[j], acc[i][j]);
  }

#pragma unroll
  for (int j = 0; j < 4; j++) {
    const int nn = n0 + wn * 64 + j * 16 + rl;
    const float bj = bias[nn];
#pragma unroll
    for (int i = 0; i < 2; i++) {
      const int mm = m0 + wm * 32 + i * 16 + qd * 4;
#pragma unroll
      for (int r = 0; r < 4; r++)
        out[(size_t)(mm + r) * 1024 + nn] = acc[i][j][r] + bj;
    }
  }
}

// ---------------- launch ----------------
extern "C" void kernel_launch(void* const* d_in, const int* in_sizes, int n_in,
                              void* d_out, int out_size, void* d_ws, size_t ws_size,
                              hipStream_t stream) {
  const float* query = (const float*)d_in[0];
  const float* key   = (const float*)d_in[1];
  const float* value = (const float*)d_in[2];
  const float* Wq = (const float*)d_in[3];
  const float* bq = (const float*)d_in[4];
  const float* Wk = (const float*)d_in[5];
  const float* bk = (const float*)d_in[6];
  const float* Wv = (const float*)d_in[7];
  const float* bv = (const float*)d_in[8];
  const float* Wo = (const float*)d_in[9];
  const float* bo = (const float*)d_in[10];

  // workspace: f16 region 67 MB + f16 partials 16 MB + ML 1 MB
  _Float16* ws = (_Float16*)d_ws;
  _Float16* Xf = ws;                          // 3*E8: query,key,value fp16
  _Float16* Wf = ws + 3 * (size_t)E8;         // 4*M1: Wq,Wk,Wv,Wo fp16
  _Float16* Qh = Wf + 4 * (size_t)M1;         // E8 [B,H,S,HD] (pre-scaled)
  _Float16* Kh = Qh + (size_t)E8;             // E8 [B,H,S,HD]
  _Float16* Vt = Kh + (size_t)E8;             // E8 [B,H,HD,S]
  _Float16* Xa = Vt + (size_t)E8;             // E8 [B,S,D]
  _Float16* Op = Xa + (size_t)E8;             // [2][NROW][64] f16
  float2*   ML = (float2*)(Op + 2 * (size_t)NROW * 64);  // [2][NROW]

  prep_all<<<16384, 256, 0, stream>>>(query, key, value, Wq, Wk, Wv, Wo, Xf, Wf);
  gemm_qkv<<<dim3(8, 32, 3), 256, 0, stream>>>(Xf, Wf, bq, bk, bv, Qh);
  attn_kernel<<<dim3(16, 2, 32), 256, 0, stream>>>(Qh, Kh, Vt, Op, ML);
  merge_kernel<<<4096, 256, 0, stream>>>(Op, ML, Xa);
  gemm_out<<<dim3(8, 64), 256, 0, stream>>>(Xa, Wf + 3 * (size_t)M1, bo, (float*)d_out);
}